// Round 14
// baseline (415.069 us; speedup 1.0000x reference)
//
#include <hip/hip_runtime.h>

#define TT 256
#define BB 512
#define DD 128
#define HH 50
#define KK 5
#define AA 4
#define NROW 131072      // T*B rows

#define R25(X) X(0) X(1) X(2) X(3) X(4) X(5) X(6) X(7) X(8) X(9) \
  X(10) X(11) X(12) X(13) X(14) X(15) X(16) X(17) X(18) X(19) \
  X(20) X(21) X(22) X(23) X(24)

typedef _Float16 half4 __attribute__((ext_vector_type(4)));
typedef float f32x4 __attribute__((ext_vector_type(4)));

// ---------------- K0: weight prep ----------------
__global__ void k0_prep(const float* __restrict__ W_in,
                        const float* __restrict__ W_ctx,
                        const float* __restrict__ W_key,
                        const float* __restrict__ W_q,
                        const float* __restrict__ b_key,
                        const float* __restrict__ b_q,
                        float* __restrict__ WT, float* __restrict__ WHT,
                        float* __restrict__ WK2T, float* __restrict__ bias2) {
  int i = blockIdx.x * 256 + threadIdx.x;
  if (i < DD * 52) {
    int j = i / 52, h = i % 52;
    WT[i] = (h < HH) ? W_in[h * DD + j] : 0.f;
  }
  if (i < HH * 52) {
    int j = i / 52, h = i % 52;
    WHT[i] = (h < HH) ? W_ctx[h * (2 * HH) + HH + j] : 0.f;
  }
  if (i < HH * 64) {
    int j = i >> 6, l = i & 63;
    float v = 0.f;
    if (l < HH) v = W_ctx[l * (2 * HH) + j];
    else if (l < HH + KK) v = W_key[(l - HH) * HH + j];
    else if (l < HH + 2 * KK) v = W_q[(l - HH - KK) * HH + j];
    WK2T[i] = v;
  }
  if (i < 64) {
    float bv = 0.f;
    if (i >= HH && i < HH + KK) bv = b_key[i - HH];
    else if (i >= HH + KK && i < HH + 2 * KK) bv = b_q[i - HH - KK];
    bias2[i] = bv;
  }
}

// ---------------- K1a: h = relu(x@W_in^T + b_in), 2 passes x 25 accums ----
__global__ __launch_bounds__(256) void k1a(const float* __restrict__ x,
                                           const float* __restrict__ WT,
                                           const float* __restrict__ b_in,
                                           float* __restrict__ hT) {
  __shared__ float xs[256 * 17];
  const int tid = threadIdx.x;
  const int row = blockIdx.x * 256 + tid;
  const float* __restrict__ xblk = x + (size_t)blockIdx.x * 256 * DD;

#pragma unroll 1
  for (int hp = 0; hp < 2; ++hp) {
    const int hb = hp * 25;
#define DECLA(i) float a##i = b_in[hb + i];
    R25(DECLA)

#pragma unroll 1
    for (int jb = 0; jb < 8; ++jb) {
      __syncthreads();
#pragma unroll
      for (int u = 0; u < 4; ++u) {
        const int f = tid + u * 256;
        const int r = f >> 2, c4 = f & 3;
        const float4 v = *reinterpret_cast<const float4*>(
            xblk + (size_t)r * DD + jb * 16 + c4 * 4);
        float* d = &xs[r * 17 + c4 * 4];
        d[0] = v.x; d[1] = v.y; d[2] = v.z; d[3] = v.w;
      }
      __syncthreads();
      const float* __restrict__ xrow = &xs[tid * 17];
#pragma unroll
      for (int cc = 0; cc < 16; cc += 4) {
        const int j = jb * 16 + cc;
        const float xv0 = xrow[cc + 0];
        const float xv1 = xrow[cc + 1];
        const float xv2 = xrow[cc + 2];
        const float xv3 = xrow[cc + 3];
        const float* __restrict__ w0 = WT + (j + 0) * 52 + hb;
        const float* __restrict__ w1 = WT + (j + 1) * 52 + hb;
        const float* __restrict__ w2 = WT + (j + 2) * 52 + hb;
        const float* __restrict__ w3 = WT + (j + 3) * 52 + hb;
#define FMA25(i)                  \
  a##i = fmaf(xv0, w0[i], a##i);  \
  a##i = fmaf(xv1, w1[i], a##i);  \
  a##i = fmaf(xv2, w2[i], a##i);  \
  a##i = fmaf(xv3, w3[i], a##i);
        R25(FMA25)
      }
    }

#define STA(i) hT[(size_t)(hb + i) * NROW + row] = fmaxf(a##i, 0.f);
    R25(STA)
  }
}

// ---------------- K1b: g = h @ Wh^T + b_ctx -> f16, fragment-ordered -------
// gh[(b*TT + t)*64 + h] (_Float16), slots 50-63 zeroed.
__global__ __launch_bounds__(256) void k1b(const float* __restrict__ hT,
                                           const float* __restrict__ WHT,
                                           const float* __restrict__ b_ctx,
                                           _Float16* __restrict__ gh) {
  const int row = blockIdx.x * 256 + threadIdx.x;
  const int b = row & (BB - 1);
  const int t = row >> 9;
  _Float16* __restrict__ gr = gh + ((size_t)b * TT + t) * 64;

#pragma unroll 1
  for (int gp = 0; gp < 2; ++gp) {
    const int gb = gp * 25;
#define DECLG(i) float a##i = b_ctx[gb + i];
    R25(DECLG)

#pragma unroll 5
    for (int s = 0; s < HH; ++s) {
      const float hv = hT[(size_t)s * NROW + row];
      const float* __restrict__ wh = WHT + s * 52 + gb;
#define GFMA(i) a##i = fmaf(hv, wh[i], a##i);
      R25(GFMA)
    }

#define H4(p, q, r, s) \
  { half4 v; v[0] = (_Float16)(p); v[1] = (_Float16)(q); \
    v[2] = (_Float16)(r); v[3] = (_Float16)(s); \
    *reinterpret_cast<half4*>(gr + _slot) = v; }
    if (gp == 0) {  // h 0..24 -> slots 0..24
      int _slot;
      _slot = 0;  H4(a0, a1, a2, a3)
      _slot = 4;  H4(a4, a5, a6, a7)
      _slot = 8;  H4(a8, a9, a10, a11)
      _slot = 12; H4(a12, a13, a14, a15)
      _slot = 16; H4(a16, a17, a18, a19)
      _slot = 20; H4(a20, a21, a22, a23)
      gr[24] = (_Float16)a24;
    } else {  // h 25..49 -> slots 25..49; zero 50..63
      int _slot;
      gr[25] = (_Float16)a0;
      gr[26] = (_Float16)a1;
      gr[27] = (_Float16)a2;
      _slot = 28; H4(a3, a4, a5, a6)
      _slot = 32; H4(a7, a8, a9, a10)
      _slot = 36; H4(a11, a12, a13, a14)
      _slot = 40; H4(a15, a16, a17, a18)
      _slot = 44; H4(a19, a20, a21, a22)
      gr[48] = (_Float16)a23;
      gr[49] = (_Float16)a24;
      gr[50] = (_Float16)0.f;
      gr[51] = (_Float16)0.f;
      _slot = 52; H4(0.f, 0.f, 0.f, 0.f)
      _slot = 56; H4(0.f, 0.f, 0.f, 0.f)
      _slot = 60; H4(0.f, 0.f, 0.f, 0.f)
    }
  }
}

// ---------------- K2: MFMA-batched recurrence (32 blocks x 1 wave) ---------
// Recurrence math unchanged (verified R13). Fix: all per-step output goes to
// LDS (cbuf/kqb_l) and is flushed COALESCED every 8 steps — the R13 regress
// was ~380 scattered cache lines/step from per-lane global stores. Single
// wave per block -> in-wave DS ordering, no barriers needed.
__global__ __launch_bounds__(64, 1) void k2_mfma(
    const _Float16* __restrict__ gh, const float* __restrict__ WK2T,
    const float* __restrict__ bias2, const float* __restrict__ fc,
    float* __restrict__ ctxg, float* __restrict__ kqg) {
  __shared__ __align__(16) float cbuf[8 * 16 * 52];   // [st][chain][h0..51]
  __shared__ float kqb_l[8 * 16 * 12];                // [st][chain][row-50]
  const int lane = threadIdx.x;
  const int lrow = lane & 15, lgrp = lane >> 4;
  const int chain0 = blockIdx.x * 16;
  const int chain = chain0 + lrow;

#define DECLWF(m, kk)                                                       \
  half4 wf_##m##_##kk;                                                      \
  {                                                                         \
    const int j0 = (kk) * 16 + 4 * lgrp;                                    \
    wf_##m##_##kk[0] = (_Float16)((j0 + 0 < HH) ? WK2T[(j0 + 0) * 64 + (m) * 16 + lrow] : 0.f); \
    wf_##m##_##kk[1] = (_Float16)((j0 + 1 < HH) ? WK2T[(j0 + 1) * 64 + (m) * 16 + lrow] : 0.f); \
    wf_##m##_##kk[2] = (_Float16)((j0 + 2 < HH) ? WK2T[(j0 + 2) * 64 + (m) * 16 + lrow] : 0.f); \
    wf_##m##_##kk[3] = (_Float16)((j0 + 3 < HH) ? WK2T[(j0 + 3) * 64 + (m) * 16 + lrow] : 0.f); \
  }
  DECLWF(0, 0) DECLWF(0, 1) DECLWF(0, 2) DECLWF(0, 3)
  DECLWF(1, 0) DECLWF(1, 1) DECLWF(1, 2) DECLWF(1, 3)
  DECLWF(2, 0) DECLWF(2, 1) DECLWF(2, 2) DECLWF(2, 3)
  DECLWF(3, 0) DECLWF(3, 1) DECLWF(3, 2) DECLWF(3, 3)

  // m=3 rows: 48 + 4*lgrp + r; key/q rows 50-59
  const float bias_0 = bias2[48 + 4 * lgrp + 0];
  const float bias_1 = bias2[48 + 4 * lgrp + 1];
  const float bias_2 = bias2[48 + 4 * lgrp + 2];
  const float bias_3 = bias2[48 + 4 * lgrp + 3];
#define KQR(r)                                            \
  const int row_##r = 48 + 4 * lgrp + r;                  \
  const bool kv_##r = (row_##r >= 50 && row_##r < 60);
  KQR(0) KQR(1) KQR(2) KQR(3)

#define DECLBF(kk)                                                  \
  half4 bf_##kk;                                                    \
  {                                                                 \
    const int j0 = (kk) * 16 + 4 * lgrp;                            \
    bf_##kk[0] = (_Float16)((j0 + 0 < HH) ? fc[j0 + 0] : 0.f);      \
    bf_##kk[1] = (_Float16)((j0 + 1 < HH) ? fc[j0 + 1] : 0.f);      \
    bf_##kk[2] = (_Float16)((j0 + 2 < HH) ? fc[j0 + 2] : 0.f);      \
    bf_##kk[3] = (_Float16)((j0 + 3 < HH) ? fc[j0 + 3] : 0.f);      \
  }
  DECLBF(0) DECLBF(1) DECLBF(2) DECLBF(3)

  // ctx[t=0] = c0 for this block's 16 chains
  for (int i = lane; i < 16 * HH; i += 64) {
    const int c = i / HH, h = i - c * HH;
    ctxg[((size_t)(chain0 + c) * 257 + 0) * HH + h] = fc[h];
  }

  const _Float16* __restrict__ ghp =
      gh + (size_t)chain * TT * 64 + 4 * lgrp;

  half4 gA0 = *(const half4*)(ghp + 0 * 64 + 0);
  half4 gA1 = *(const half4*)(ghp + 0 * 64 + 16);
  half4 gA2 = *(const half4*)(ghp + 0 * 64 + 32);
  half4 gA3 = *(const half4*)(ghp + 0 * 64 + 48);
  half4 gB0 = *(const half4*)(ghp + 1 * 64 + 0);
  half4 gB1 = *(const half4*)(ghp + 1 * 64 + 16);
  half4 gB2 = *(const half4*)(ghp + 1 * 64 + 32);
  half4 gB3 = *(const half4*)(ghp + 1 * 64 + 48);

  const f32x4 zf = {0.f, 0.f, 0.f, 0.f};

#define MM(D, A, B) D = __builtin_amdgcn_mfma_f32_16x16x16f16(A, B, D, 0, 0, 0);
#define MSTEP(T, G0, G1, G2, G3, TPF)                                      \
  {                                                                        \
    f32x4 d0 = zf, d1 = zf, d2 = zf, d3 = zf;                              \
    MM(d0, wf_0_0, bf_0) MM(d1, wf_1_0, bf_0)                              \
    MM(d2, wf_2_0, bf_0) MM(d3, wf_3_0, bf_0)                              \
    MM(d0, wf_0_1, bf_1) MM(d1, wf_1_1, bf_1)                              \
    MM(d2, wf_2_1, bf_1) MM(d3, wf_3_1, bf_1)                              \
    MM(d0, wf_0_2, bf_2) MM(d1, wf_1_2, bf_2)                              \
    MM(d2, wf_2_2, bf_2) MM(d3, wf_3_2, bf_2)                              \
    MM(d0, wf_0_3, bf_3) MM(d1, wf_1_3, bf_3)                              \
    MM(d2, wf_2_3, bf_3) MM(d3, wf_3_3, bf_3)                              \
    float* kq = &kqb_l[((T)&7) * 192 + lrow * 12];                         \
    if (kv_0) kq[row_0 - 50] = d3[0] + bias_0;                             \
    if (kv_1) kq[row_1 - 50] = d3[1] + bias_1;                             \
    if (kv_2) kq[row_2 - 50] = d3[2] + bias_2;                             \
    if (kv_3) kq[row_3 - 50] = d3[3] + bias_3;                             \
    const float cn_0_0 = fmaxf(d0[0] + (float)G0[0], 0.f);                 \
    const float cn_0_1 = fmaxf(d0[1] + (float)G0[1], 0.f);                 \
    const float cn_0_2 = fmaxf(d0[2] + (float)G0[2], 0.f);                 \
    const float cn_0_3 = fmaxf(d0[3] + (float)G0[3], 0.f);                 \
    const float cn_1_0 = fmaxf(d1[0] + (float)G1[0], 0.f);                 \
    const float cn_1_1 = fmaxf(d1[1] + (float)G1[1], 0.f);                 \
    const float cn_1_2 = fmaxf(d1[2] + (float)G1[2], 0.f);                 \
    const float cn_1_3 = fmaxf(d1[3] + (float)G1[3], 0.f);                 \
    const float cn_2_0 = fmaxf(d2[0] + (float)G2[0], 0.f);                 \
    const float cn_2_1 = fmaxf(d2[1] + (float)G2[1], 0.f);                 \
    const float cn_2_2 = fmaxf(d2[2] + (float)G2[2], 0.f);                 \
    const float cn_2_3 = fmaxf(d2[3] + (float)G2[3], 0.f);                 \
    const float cn_3_0 = fmaxf(d3[0] + (float)G3[0], 0.f);                 \
    const float cn_3_1 = fmaxf(d3[1] + (float)G3[1], 0.f);                 \
    const float cn_3_2 = fmaxf(d3[2] + (float)G3[2], 0.f);                 \
    const float cn_3_3 = fmaxf(d3[3] + (float)G3[3], 0.f);                 \
    G0 = *(const half4*)(ghp + (size_t)((TPF) < TT ? (TPF) : TT - 1) * 64 + 0);  \
    G1 = *(const half4*)(ghp + (size_t)((TPF) < TT ? (TPF) : TT - 1) * 64 + 16); \
    G2 = *(const half4*)(ghp + (size_t)((TPF) < TT ? (TPF) : TT - 1) * 64 + 32); \
    G3 = *(const half4*)(ghp + (size_t)((TPF) < TT ? (TPF) : TT - 1) * 64 + 48); \
    float* cb = &cbuf[((T)&7) * 832 + lrow * 52 + 4 * lgrp];               \
    *reinterpret_cast<float4*>(cb + 0) =                                   \
        make_float4(cn_0_0, cn_0_1, cn_0_2, cn_0_3);                       \
    *reinterpret_cast<float4*>(cb + 16) =                                  \
        make_float4(cn_1_0, cn_1_1, cn_1_2, cn_1_3);                       \
    *reinterpret_cast<float4*>(cb + 32) =                                  \
        make_float4(cn_2_0, cn_2_1, cn_2_2, cn_2_3);                       \
    if (lgrp == 0)                                                         \
      *reinterpret_cast<float4*>(cb + 48) =                                \
          make_float4(cn_3_0, cn_3_1, cn_3_2, cn_3_3);                     \
    bf_0[0] = (_Float16)cn_0_0; bf_0[1] = (_Float16)cn_0_1;                \
    bf_0[2] = (_Float16)cn_0_2; bf_0[3] = (_Float16)cn_0_3;                \
    bf_1[0] = (_Float16)cn_1_0; bf_1[1] = (_Float16)cn_1_1;                \
    bf_1[2] = (_Float16)cn_1_2; bf_1[3] = (_Float16)cn_1_3;                \
    bf_2[0] = (_Float16)cn_2_0; bf_2[1] = (_Float16)cn_2_1;                \
    bf_2[2] = (_Float16)cn_2_2; bf_2[3] = (_Float16)cn_2_3;                \
    bf_3[0] = (_Float16)cn_3_0; bf_3[1] = (_Float16)cn_3_1;                \
    bf_3[2] = (_Float16)cn_3_2; bf_3[3] = (_Float16)cn_3_3;                \
  }

#pragma unroll 1
  for (int tg = 0; tg < TT; tg += 8) {
#pragma unroll 1
    for (int tp = 0; tp < 8; tp += 2) {
      const int t = tg + tp;
      MSTEP(t, gA0, gA1, gA2, gA3, t + 2)
      MSTEP(t + 1, gB0, gB1, gB2, gB3, t + 3)
    }
    // coalesced flush of 8 steps (in-wave DS ordering; no barrier needed)
    // c: cbuf[st][ch][0..49] -> ctxg[chain0+ch][tg+st+1][0..49]
    for (int i = lane; i < 3200; i += 64) {
      const int st = i / 400;
      const int rem = i - st * 400;
      const int ch = rem / 25;
      const int j = rem - ch * 25;
      const float2 v =
          *reinterpret_cast<const float2*>(&cbuf[st * 832 + ch * 52 + 2 * j]);
      *reinterpret_cast<float2*>(
          &ctxg[((size_t)(chain0 + ch) * 257 + (tg + st + 1)) * HH + 2 * j]) =
          v;
    }
    // kq: kqb_l[st][ch][row] -> kqg[(chain0+ch)*10+row][tg+st]
    for (int i = lane; i < 1280; i += 64) {
      const int ch = i / 80;
      const int rem = i - ch * 80;
      const int row = rem >> 3;
      const int st = rem & 7;
      kqg[((size_t)(chain0 + ch) * 10 + row) * 257 + (tg + st)] =
          kqb_l[st * 192 + ch * 12 + row];
    }
  }

  {  // tail: key/q of c_TT at index TT (one scattered store, negligible)
    f32x4 d3 = zf;
    MM(d3, wf_3_0, bf_0) MM(d3, wf_3_1, bf_1)
    MM(d3, wf_3_2, bf_2) MM(d3, wf_3_3, bf_3)
    if (kv_0) kqg[((size_t)chain * 10 + row_0 - 50) * 257 + TT] = d3[0] + bias_0;
    if (kv_1) kqg[((size_t)chain * 10 + row_1 - 50) * 257 + TT] = d3[1] + bias_1;
    if (kv_2) kqg[((size_t)chain * 10 + row_2 - 50) * 257 + TT] = d3[2] + bias_2;
    if (kv_3) kqg[((size_t)chain * 10 + row_3 - 50) * 257 + TT] = d3[3] + bias_3;
  }
}

// ---------------- K3: MFMA flash attention, LDS-staged ---------------------
// keys: kqg[b][k][s] (k 0-4); q for step t: kqg[b][5+k][t+1].
__global__ __launch_bounds__(256, 4) void k3_attn(
    const float* __restrict__ ctxg, const float* __restrict__ kqg,
    const float* __restrict__ W_act, const float* __restrict__ b_act,
    float* __restrict__ out) {
  __shared__ __align__(16) float ct[64 * 66];   // [s_local][h]
  __shared__ __align__(16) float k_l[8 * 68];   // [k][s_local], rows 5-7 = 0
  __shared__ __align__(16) float o_l[64 * 66];  // [t_local][h]
  __shared__ float su_l[64];

  const int tid = threadIdx.x;
  const int bid = blockIdx.x;
  const int chunk = 3 - (bid >> 9);  // heavy-first
  const int b = bid & 511;
  const int tbase = chunk * 64;
  const int nst = min(tbase + 66, 257);
  const int ntiles = (nst + 63) >> 6;
  const int wave = tid >> 6;
  const int lane = tid & 63;
  const int lrow = lane & 15;
  const int lgrp = lane >> 4;
  const int tw = tbase + wave * 16;

  if (tid < 3 * 68) k_l[5 * 68 + tid] = 0.f;

  half4 qf;
#pragma unroll
  for (int i = 0; i < 4; ++i) {
    const int k = 4 * lgrp + i;
    qf[i] = (_Float16)((k < KK)
                           ? kqg[((size_t)b * 10 + 5 + k) * 257 + tw + lrow + 1]
                           : 0.f);
  }

  const f32x4 zf = {0.f, 0.f, 0.f, 0.f};
  f32x4 acc0 = zf, acc1 = zf, acc2 = zf, acc3 = zf;
  float su = 0.f;

#pragma unroll 1
  for (int tile = 0; tile < ntiles; ++tile) {
    __syncthreads();
    {
      const int r = tid >> 2;
      const int c0 = (tid & 3) * 16;
      const int srow = tile * 64 + r;
      const float* src = ctxg + ((size_t)b * 257 + srow) * HH;
      const bool sv = (srow < nst);
#pragma unroll
      for (int u = 0; u < 8; ++u) {
        const int c = c0 + u * 2;
        float2 v = make_float2(0.f, 0.f);
        if (sv && c < HH) v = *reinterpret_cast<const float2*>(src + c);
        *reinterpret_cast<float2*>(&ct[r * 66 + c]) = v;
      }
    }
    {
      for (int i = tid; i < KK * 64; i += 256) {
        const int k = i >> 6, sl = i & 63;
        const int s = tile * 64 + sl;
        k_l[k * 68 + sl] =
            (s <= TT) ? kqg[((size_t)b * 10 + k) * 257 + s] : 0.f;
      }
    }
    __syncthreads();

    if (tile * 64 <= tw + 16) {
#pragma unroll 1
      for (int su16 = 0; su16 < 4; ++su16) {
        const int sb = tile * 64 + su16 * 16;
        if (sb > tw + 16) break;

        half4 kf;
#pragma unroll
        for (int i = 0; i < 4; ++i)
          kf[i] = (_Float16)k_l[(4 * lgrp + i) * 68 + su16 * 16 + lrow];

        const f32x4 sc =
            __builtin_amdgcn_mfma_f32_16x16x16f16(kf, qf, zf, 0, 0, 0);

        half4 pa;
#pragma unroll
        for (int r = 0; r < 4; ++r) {
          const int s = sb + 4 * lgrp + r;
          const float p = (s <= tw + lrow + 1) ? __expf(sc[r]) : 0.f;
          su += p;
          pa[r] = (_Float16)p;
        }

        const int vbase = su16 * 16 + 4 * lgrp;
#define PVHT(HT, ACC)                                                     \
  {                                                                       \
    half4 vf;                                                             \
    vf[0] = (_Float16)ct[(vbase + 0) * 66 + lrow + 16 * HT];              \
    vf[1] = (_Float16)ct[(vbase + 1) * 66 + lrow + 16 * HT];              \
    vf[2] = (_Float16)ct[(vbase + 2) * 66 + lrow + 16 * HT];              \
    vf[3] = (_Float16)ct[(vbase + 3) * 66 + lrow + 16 * HT];              \
    ACC = __builtin_amdgcn_mfma_f32_16x16x16f16(pa, vf, ACC, 0, 0, 0);    \
  }
        PVHT(0, acc0) PVHT(1, acc1) PVHT(2, acc2) PVHT(3, acc3)
      }
    }
  }

  su += __shfl_xor(su, 16, 64);
  su += __shfl_xor(su, 32, 64);
  if (lane < 16) su_l[wave * 16 + lane] = su;

#pragma unroll
  for (int r = 0; r < 4; ++r) {
    const int trow = wave * 16 + 4 * lgrp + r;
    o_l[trow * 66 + lrow + 0] = acc0[r];
    o_l[trow * 66 + lrow + 16] = acc1[r];
    o_l[trow * 66 + lrow + 32] = acc2[r];
    o_l[trow * 66 + lrow + 48] = acc3[r];
  }
  __syncthreads();

  {
    const int tl = tid >> 2;
    const int a = tid & 3;
    const float inv = 1.f / su_l[tl];
    const float* orow = &o_l[tl * 66];
    const float* wrow = W_act + a * HH;
    float s0 = 0.f, s1 = 0.f;
#pragma unroll
    for (int h = 0; h < HH; h += 2) {
      s0 = fmaf(orow[h], wrow[h], s0);
      s1 = fmaf(orow[h + 1], wrow[h + 1], s1);
    }
    out[((size_t)(tbase + tl) * BB + b) * AA + a] =
        fmaf(s0 + s1, inv, b_act[a]);
  }
}

extern "C" void kernel_launch(void* const* d_in, const int* in_sizes, int n_in,
                              void* d_out, int out_size, void* d_ws,
                              size_t ws_size, hipStream_t stream) {
  const float* x = (const float*)d_in[0];
  const float* W_in = (const float*)d_in[1];
  const float* b_in = (const float*)d_in[2];
  const float* W_ctx = (const float*)d_in[3];
  const float* b_ctx = (const float*)d_in[4];
  const float* W_key = (const float*)d_in[5];
  const float* b_key = (const float*)d_in[6];
  const float* W_q = (const float*)d_in[7];
  const float* b_q = (const float*)d_in[8];
  const float* fc = (const float*)d_in[9];
  const float* W_act = (const float*)d_in[10];
  const float* b_act = (const float*)d_in[11];
  float* out = (float*)d_out;
  float* ws = (float*)d_ws;

  float* WT = ws;                                   // 128*52
  float* WHT = ws + 8192;                           // 50*52
  float* WK2T = ws + 12288;                         // 50*64
  float* bias2 = ws + 15616;                        // 64
  _Float16* gh = (_Float16*)(ws + 16384);           // 131072*64 f16
  float* hbufT = ws + 16384 + 4194304;              // 50*131072 f32
  float* ctxg = hbufT;                              // alias: dead after k1b
  float* kqg = ctxg + (size_t)BB * 257 * HH;        // 512*10*257
  // total ~48.4 MB

  hipLaunchKernelGGL(k0_prep, dim3(26), dim3(256), 0, stream, W_in, W_ctx,
                     W_key, W_q, b_key, b_q, WT, WHT, WK2T, bias2);
  hipLaunchKernelGGL(k1a, dim3(512), dim3(256), 0, stream, x, WT, b_in, hbufT);
  hipLaunchKernelGGL(k1b, dim3(512), dim3(256), 0, stream, hbufT, WHT, b_ctx,
                     gh);
  hipLaunchKernelGGL(k2_mfma, dim3(32), dim3(64), 0, stream, gh, WK2T, bias2,
                     fc, ctxg, kqg);
  hipLaunchKernelGGL(k3_attn, dim3(2048), dim3(256), 0, stream, ctxg, kqg,
                     W_act, b_act, out);
}

// Round 16
// 310.637 us; speedup vs baseline: 1.3362x; 1.3362x over previous
//
#include <hip/hip_runtime.h>

#define TT 256
#define BB 512
#define DD 128
#define HH 50
#define KK 5
#define AA 4
#define NROW 131072      // T*B rows

#define R25(X) X(0) X(1) X(2) X(3) X(4) X(5) X(6) X(7) X(8) X(9) \
  X(10) X(11) X(12) X(13) X(14) X(15) X(16) X(17) X(18) X(19) \
  X(20) X(21) X(22) X(23) X(24)

typedef _Float16 half4 __attribute__((ext_vector_type(4)));
typedef float f32x4 __attribute__((ext_vector_type(4)));

// ---------------- K0: weight prep ----------------
__global__ void k0_prep(const float* __restrict__ W_in,
                        const float* __restrict__ W_ctx,
                        const float* __restrict__ W_key,
                        const float* __restrict__ W_q,
                        const float* __restrict__ b_key,
                        const float* __restrict__ b_q,
                        float* __restrict__ WT, float* __restrict__ WHT,
                        float* __restrict__ WK2T, float* __restrict__ bias2) {
  int i = blockIdx.x * 256 + threadIdx.x;
  if (i < DD * 52) {
    int j = i / 52, h = i % 52;
    WT[i] = (h < HH) ? W_in[h * DD + j] : 0.f;
  }
  if (i < HH * 52) {
    int j = i / 52, h = i % 52;
    WHT[i] = (h < HH) ? W_ctx[h * (2 * HH) + HH + j] : 0.f;
  }
  if (i < HH * 64) {
    int j = i >> 6, l = i & 63;
    float v = 0.f;
    if (l < HH) v = W_ctx[l * (2 * HH) + j];
    else if (l < HH + KK) v = W_key[(l - HH) * HH + j];
    else if (l < HH + 2 * KK) v = W_q[(l - HH - KK) * HH + j];
    WK2T[i] = v;
  }
  if (i < 64) {
    float bv = 0.f;
    if (i >= HH && i < HH + KK) bv = b_key[i - HH];
    else if (i >= HH + KK && i < HH + 2 * KK) bv = b_q[i - HH - KK];
    bias2[i] = bv;
  }
}

// ---------------- K1a: h = relu(x@W_in^T + b_in), 2 passes x 25 accums ----
__global__ __launch_bounds__(256) void k1a(const float* __restrict__ x,
                                           const float* __restrict__ WT,
                                           const float* __restrict__ b_in,
                                           float* __restrict__ hT) {
  __shared__ float xs[256 * 17];
  const int tid = threadIdx.x;
  const int row = blockIdx.x * 256 + tid;
  const float* __restrict__ xblk = x + (size_t)blockIdx.x * 256 * DD;

#pragma unroll 1
  for (int hp = 0; hp < 2; ++hp) {
    const int hb = hp * 25;
#define DECLA(i) float a##i = b_in[hb + i];
    R25(DECLA)

#pragma unroll 1
    for (int jb = 0; jb < 8; ++jb) {
      __syncthreads();
#pragma unroll
      for (int u = 0; u < 4; ++u) {
        const int f = tid + u * 256;
        const int r = f >> 2, c4 = f & 3;
        const float4 v = *reinterpret_cast<const float4*>(
            xblk + (size_t)r * DD + jb * 16 + c4 * 4);
        float* d = &xs[r * 17 + c4 * 4];
        d[0] = v.x; d[1] = v.y; d[2] = v.z; d[3] = v.w;
      }
      __syncthreads();
      const float* __restrict__ xrow = &xs[tid * 17];
#pragma unroll
      for (int cc = 0; cc < 16; cc += 4) {
        const int j = jb * 16 + cc;
        const float xv0 = xrow[cc + 0];
        const float xv1 = xrow[cc + 1];
        const float xv2 = xrow[cc + 2];
        const float xv3 = xrow[cc + 3];
        const float* __restrict__ w0 = WT + (j + 0) * 52 + hb;
        const float* __restrict__ w1 = WT + (j + 1) * 52 + hb;
        const float* __restrict__ w2 = WT + (j + 2) * 52 + hb;
        const float* __restrict__ w3 = WT + (j + 3) * 52 + hb;
#define FMA25(i)                  \
  a##i = fmaf(xv0, w0[i], a##i);  \
  a##i = fmaf(xv1, w1[i], a##i);  \
  a##i = fmaf(xv2, w2[i], a##i);  \
  a##i = fmaf(xv3, w3[i], a##i);
        R25(FMA25)
      }
    }

#define STA(i) hT[(size_t)(hb + i) * NROW + row] = fmaxf(a##i, 0.f);
    R25(STA)
  }
}

// ---------------- K1b: g = h @ Wh^T + b_ctx -> f16, fragment-ordered -------
__global__ __launch_bounds__(256) void k1b(const float* __restrict__ hT,
                                           const float* __restrict__ WHT,
                                           const float* __restrict__ b_ctx,
                                           _Float16* __restrict__ gh) {
  const int row = blockIdx.x * 256 + threadIdx.x;
  const int b = row & (BB - 1);
  const int t = row >> 9;
  _Float16* __restrict__ gr = gh + ((size_t)b * TT + t) * 64;

#pragma unroll 1
  for (int gp = 0; gp < 2; ++gp) {
    const int gb = gp * 25;
#define DECLG(i) float a##i = b_ctx[gb + i];
    R25(DECLG)

#pragma unroll 5
    for (int s = 0; s < HH; ++s) {
      const float hv = hT[(size_t)s * NROW + row];
      const float* __restrict__ wh = WHT + s * 52 + gb;
#define GFMA(i) a##i = fmaf(hv, wh[i], a##i);
      R25(GFMA)
    }

#define H4(p, q, r, s) \
  { half4 v; v[0] = (_Float16)(p); v[1] = (_Float16)(q); \
    v[2] = (_Float16)(r); v[3] = (_Float16)(s); \
    *reinterpret_cast<half4*>(gr + _slot) = v; }
    if (gp == 0) {
      int _slot;
      _slot = 0;  H4(a0, a1, a2, a3)
      _slot = 4;  H4(a4, a5, a6, a7)
      _slot = 8;  H4(a8, a9, a10, a11)
      _slot = 12; H4(a12, a13, a14, a15)
      _slot = 16; H4(a16, a17, a18, a19)
      _slot = 20; H4(a20, a21, a22, a23)
      gr[24] = (_Float16)a24;
    } else {
      int _slot;
      gr[25] = (_Float16)a0;
      gr[26] = (_Float16)a1;
      gr[27] = (_Float16)a2;
      _slot = 28; H4(a3, a4, a5, a6)
      _slot = 32; H4(a7, a8, a9, a10)
      _slot = 36; H4(a11, a12, a13, a14)
      _slot = 40; H4(a15, a16, a17, a18)
      _slot = 44; H4(a19, a20, a21, a22)
      gr[48] = (_Float16)a23;
      gr[49] = (_Float16)a24;
      gr[50] = (_Float16)0.f;
      gr[51] = (_Float16)0.f;
      _slot = 52; H4(0.f, 0.f, 0.f, 0.f)
      _slot = 56; H4(0.f, 0.f, 0.f, 0.f)
      _slot = 60; H4(0.f, 0.f, 0.f, 0.f)
    }
  }
}

// ---------------- K2: MFMA-batched recurrence (32 blocks x 1 wave) ---------
// Compute core verified (R13/R14). Egress: per-step LDS writes + every-8-
// step FULLY-UNROLLED shift/mask flush (batched ds_read_b128 + coalesced
// 256B-row float4 stores). ctxg64[chain][257][64] (h linear); kqg2
// [chain][16][257]. Single wave -> in-wave DS ordering, no barriers.
__global__ __launch_bounds__(64, 1) void k2_mfma(
    const _Float16* __restrict__ gh, const float* __restrict__ WK2T,
    const float* __restrict__ bias2, const float* __restrict__ fc,
    float* __restrict__ ctxg64, float* __restrict__ kqg2) {
  __shared__ __align__(16) float cbuf[8 * 16 * 72];  // [st][ch][72]
  __shared__ float kqb2[16 * 129];                   // [ch][row*8+st], s129
  const int lane = threadIdx.x;
  const int lrow = lane & 15, lgrp = lane >> 4;
  const int chain0 = blockIdx.x * 16;
  const int chain = chain0 + lrow;

#define DECLWF(m, kk)                                                       \
  half4 wf_##m##_##kk;                                                      \
  {                                                                         \
    const int j0 = (kk) * 16 + 4 * lgrp;                                    \
    wf_##m##_##kk[0] = (_Float16)((j0 + 0 < HH) ? WK2T[(j0 + 0) * 64 + (m) * 16 + lrow] : 0.f); \
    wf_##m##_##kk[1] = (_Float16)((j0 + 1 < HH) ? WK2T[(j0 + 1) * 64 + (m) * 16 + lrow] : 0.f); \
    wf_##m##_##kk[2] = (_Float16)((j0 + 2 < HH) ? WK2T[(j0 + 2) * 64 + (m) * 16 + lrow] : 0.f); \
    wf_##m##_##kk[3] = (_Float16)((j0 + 3 < HH) ? WK2T[(j0 + 3) * 64 + (m) * 16 + lrow] : 0.f); \
  }
  DECLWF(0, 0) DECLWF(0, 1) DECLWF(0, 2) DECLWF(0, 3)
  DECLWF(1, 0) DECLWF(1, 1) DECLWF(1, 2) DECLWF(1, 3)
  DECLWF(2, 0) DECLWF(2, 1) DECLWF(2, 2) DECLWF(2, 3)
  DECLWF(3, 0) DECLWF(3, 1) DECLWF(3, 2) DECLWF(3, 3)

  const float bias_0 = bias2[48 + 4 * lgrp + 0];
  const float bias_1 = bias2[48 + 4 * lgrp + 1];
  const float bias_2 = bias2[48 + 4 * lgrp + 2];
  const float bias_3 = bias2[48 + 4 * lgrp + 3];
#define KQR(r)                                            \
  const int row_##r = 48 + 4 * lgrp + r;                  \
  const bool kv_##r = (row_##r >= 50 && row_##r < 60);
  KQR(0) KQR(1) KQR(2) KQR(3)

#define DECLBF(kk)                                                  \
  half4 bf_##kk;                                                    \
  {                                                                 \
    const int j0 = (kk) * 16 + 4 * lgrp;                            \
    bf_##kk[0] = (_Float16)((j0 + 0 < HH) ? fc[j0 + 0] : 0.f);      \
    bf_##kk[1] = (_Float16)((j0 + 1 < HH) ? fc[j0 + 1] : 0.f);      \
    bf_##kk[2] = (_Float16)((j0 + 2 < HH) ? fc[j0 + 2] : 0.f);      \
    bf_##kk[3] = (_Float16)((j0 + 3 < HH) ? fc[j0 + 3] : 0.f);      \
  }
  DECLBF(0) DECLBF(1) DECLBF(2) DECLBF(3)

  // ctx[t=0] = c0 (h>=50 written as 0; k3 reads only h<50)
  for (int i = lane; i < 16 * 64; i += 64) {
    const int c = i >> 6, h = i & 63;
    ctxg64[((size_t)(chain0 + c) * 257 + 0) * 64 + h] = (h < HH) ? fc[h] : 0.f;
  }

  const _Float16* __restrict__ ghp =
      gh + (size_t)chain * TT * 64 + 4 * lgrp;

  half4 gA0 = *(const half4*)(ghp + 0 * 64 + 0);
  half4 gA1 = *(const half4*)(ghp + 0 * 64 + 16);
  half4 gA2 = *(const half4*)(ghp + 0 * 64 + 32);
  half4 gA3 = *(const half4*)(ghp + 0 * 64 + 48);
  half4 gB0 = *(const half4*)(ghp + 1 * 64 + 0);
  half4 gB1 = *(const half4*)(ghp + 1 * 64 + 16);
  half4 gB2 = *(const half4*)(ghp + 1 * 64 + 32);
  half4 gB3 = *(const half4*)(ghp + 1 * 64 + 48);

  const f32x4 zf = {0.f, 0.f, 0.f, 0.f};

#define MM(D, A, B) D = __builtin_amdgcn_mfma_f32_16x16x16f16(A, B, D, 0, 0, 0);
#define MSTEP(T, G0, G1, G2, G3, TPF)                                      \
  {                                                                        \
    f32x4 d0 = zf, d1 = zf, d2 = zf, d3 = zf;                              \
    MM(d0, wf_0_0, bf_0) MM(d1, wf_1_0, bf_0)                              \
    MM(d2, wf_2_0, bf_0) MM(d3, wf_3_0, bf_0)                              \
    MM(d0, wf_0_1, bf_1) MM(d1, wf_1_1, bf_1)                              \
    MM(d2, wf_2_1, bf_1) MM(d3, wf_3_1, bf_1)                              \
    MM(d0, wf_0_2, bf_2) MM(d1, wf_1_2, bf_2)                              \
    MM(d2, wf_2_2, bf_2) MM(d3, wf_3_2, bf_2)                              \
    MM(d0, wf_0_3, bf_3) MM(d1, wf_1_3, bf_3)                              \
    MM(d2, wf_2_3, bf_3) MM(d3, wf_3_3, bf_3)                              \
    {                                                                      \
      float* kq = &kqb2[lrow * 129 + ((T) & 7)];                           \
      if (kv_0) kq[(row_0 - 50) * 8] = d3[0] + bias_0;                     \
      if (kv_1) kq[(row_1 - 50) * 8] = d3[1] + bias_1;                     \
      if (kv_2) kq[(row_2 - 50) * 8] = d3[2] + bias_2;                     \
      if (kv_3) kq[(row_3 - 50) * 8] = d3[3] + bias_3;                     \
    }                                                                      \
    const float cn_0_0 = fmaxf(d0[0] + (float)G0[0], 0.f);                 \
    const float cn_0_1 = fmaxf(d0[1] + (float)G0[1], 0.f);                 \
    const float cn_0_2 = fmaxf(d0[2] + (float)G0[2], 0.f);                 \
    const float cn_0_3 = fmaxf(d0[3] + (float)G0[3], 0.f);                 \
    const float cn_1_0 = fmaxf(d1[0] + (float)G1[0], 0.f);                 \
    const float cn_1_1 = fmaxf(d1[1] + (float)G1[1], 0.f);                 \
    const float cn_1_2 = fmaxf(d1[2] + (float)G1[2], 0.f);                 \
    const float cn_1_3 = fmaxf(d1[3] + (float)G1[3], 0.f);                 \
    const float cn_2_0 = fmaxf(d2[0] + (float)G2[0], 0.f);                 \
    const float cn_2_1 = fmaxf(d2[1] + (float)G2[1], 0.f);                 \
    const float cn_2_2 = fmaxf(d2[2] + (float)G2[2], 0.f);                 \
    const float cn_2_3 = fmaxf(d2[3] + (float)G2[3], 0.f);                 \
    const float cn_3_0 = fmaxf(d3[0] + (float)G3[0], 0.f);                 \
    const float cn_3_1 = fmaxf(d3[1] + (float)G3[1], 0.f);                 \
    const float cn_3_2 = fmaxf(d3[2] + (float)G3[2], 0.f);                 \
    const float cn_3_3 = fmaxf(d3[3] + (float)G3[3], 0.f);                 \
    G0 = *(const half4*)(ghp + (size_t)((TPF) < TT ? (TPF) : TT - 1) * 64 + 0);  \
    G1 = *(const half4*)(ghp + (size_t)((TPF) < TT ? (TPF) : TT - 1) * 64 + 16); \
    G2 = *(const half4*)(ghp + (size_t)((TPF) < TT ? (TPF) : TT - 1) * 64 + 32); \
    G3 = *(const half4*)(ghp + (size_t)((TPF) < TT ? (TPF) : TT - 1) * 64 + 48); \
    float* cb = &cbuf[((T) & 7) * 1152 + lrow * 72 + 4 * lgrp];            \
    *reinterpret_cast<float4*>(cb + 0) =                                   \
        make_float4(cn_0_0, cn_0_1, cn_0_2, cn_0_3);                       \
    *reinterpret_cast<float4*>(cb + 16) =                                  \
        make_float4(cn_1_0, cn_1_1, cn_1_2, cn_1_3);                       \
    *reinterpret_cast<float4*>(cb + 32) =                                  \
        make_float4(cn_2_0, cn_2_1, cn_2_2, cn_2_3);                       \
    *reinterpret_cast<float4*>(cb + 48) =                                  \
        make_float4(cn_3_0, cn_3_1, cn_3_2, cn_3_3);                       \
    bf_0[0] = (_Float16)cn_0_0; bf_0[1] = (_Float16)cn_0_1;                \
    bf_0[2] = (_Float16)cn_0_2; bf_0[3] = (_Float16)cn_0_3;                \
    bf_1[0] = (_Float16)cn_1_0; bf_1[1] = (_Float16)cn_1_1;                \
    bf_1[2] = (_Float16)cn_1_2; bf_1[3] = (_Float16)cn_1_3;                \
    bf_2[0] = (_Float16)cn_2_0; bf_2[1] = (_Float16)cn_2_1;                \
    bf_2[2] = (_Float16)cn_2_2; bf_2[3] = (_Float16)cn_2_3;                \
    bf_3[0] = (_Float16)cn_3_0; bf_3[1] = (_Float16)cn_3_1;                \
    bf_3[2] = (_Float16)cn_3_2; bf_3[3] = (_Float16)cn_3_3;                \
  }

#pragma unroll 1
  for (int tg = 0; tg < TT; tg += 8) {
#pragma unroll 1
    for (int tp = 0; tp < 8; tp += 2) {
      const int t = tg + tp;
      MSTEP(t, gA0, gA1, gA2, gA3, t + 2)
      MSTEP(t + 1, gB0, gB1, gB2, gB3, t + 3)
    }
    // --- c flush: 32 unrolled {ds_read_b128 -> float4 store}, shift/mask ---
#pragma unroll
    for (int k = 0; k < 32; ++k) {
      const int id = lane + (k << 6);
      const int st = id >> 8;
      const int ch = (id >> 4) & 15;
      const int q4 = id & 15;
      const float4 v = *reinterpret_cast<const float4*>(
          &cbuf[st * 1152 + ch * 72 + q4 * 4]);
      *reinterpret_cast<float4*>(
          &ctxg64[((size_t)(chain0 + ch) * 257 + (tg + st + 1)) * 64 +
                  q4 * 4]) = v;
    }
    // --- kq flush: 32 unrolled scalar reads/stores (rows >= 10 skipped) ---
#pragma unroll
    for (int k = 0; k < 32; ++k) {
      const int id = lane + (k << 6);
      const int ch = id >> 7;
      const int row = (id >> 3) & 15;
      const int st = id & 7;
      if (row < 10) {
        kqg2[((size_t)(chain0 + ch) * 16 + row) * 257 + (tg + st)] =
            kqb2[ch * 129 + row * 8 + st];
      }
    }
  }

  {  // tail: key/q of c_TT at index TT
    f32x4 d3 = zf;
    MM(d3, wf_3_0, bf_0) MM(d3, wf_3_1, bf_1)
    MM(d3, wf_3_2, bf_2) MM(d3, wf_3_3, bf_3)
    if (kv_0) kqg2[((size_t)chain * 16 + row_0 - 50) * 257 + TT] = d3[0] + bias_0;
    if (kv_1) kqg2[((size_t)chain * 16 + row_1 - 50) * 257 + TT] = d3[1] + bias_1;
    if (kv_2) kqg2[((size_t)chain * 16 + row_2 - 50) * 257 + TT] = d3[2] + bias_2;
    if (kv_3) kqg2[((size_t)chain * 16 + row_3 - 50) * 257 + TT] = d3[3] + bias_3;
  }
}

// ---------------- K3: MFMA flash attention, LDS-staged ---------------------
// ctx rows stride-64 (h linear); keys kqg2[b][k][s] (k 0-4); q for output
// t: kqg2[b][5+k][t+1]. FIX (R16): k_l is 16 rows, rows 5-15 hard-zeroed —
// the QK A-fragment reads rows 0-15, and rows 8-15 previously read PAST the
// 8-row array into ambient LDS (0 x inf/NaN junk = NaN; latent since R9).
__global__ __launch_bounds__(256, 4) void k3_attn(
    const float* __restrict__ ctxg64, const float* __restrict__ kqg2,
    const float* __restrict__ W_act, const float* __restrict__ b_act,
    float* __restrict__ out) {
  __shared__ __align__(16) float ct[64 * 66];    // [s_local][h]
  __shared__ __align__(16) float k_l[16 * 68];   // [k][s_local], rows 5-15=0
  __shared__ __align__(16) float o_l[64 * 66];   // [t_local][h]
  __shared__ float su_l[64];

  const int tid = threadIdx.x;
  const int bid = blockIdx.x;
  const int chunk = 3 - (bid >> 9);  // heavy-first
  const int b = bid & 511;
  const int tbase = chunk * 64;
  const int nst = min(tbase + 66, 257);
  const int ntiles = (nst + 63) >> 6;
  const int wave = tid >> 6;
  const int lane = tid & 63;
  const int lrow = lane & 15;
  const int lgrp = lane >> 4;
  const int tw = tbase + wave * 16;

  for (int i = tid; i < 11 * 68; i += 256) k_l[5 * 68 + i] = 0.f;

  half4 qf;
#pragma unroll
  for (int i = 0; i < 4; ++i) {
    const int k = 4 * lgrp + i;
    qf[i] = (_Float16)((k < KK)
                           ? kqg2[((size_t)b * 16 + 5 + k) * 257 + tw + lrow + 1]
                           : 0.f);
  }

  const f32x4 zf = {0.f, 0.f, 0.f, 0.f};
  f32x4 acc0 = zf, acc1 = zf, acc2 = zf, acc3 = zf;
  float su = 0.f;

#pragma unroll 1
  for (int tile = 0; tile < ntiles; ++tile) {
    __syncthreads();
    {
      const int r = tid >> 2;
      const int c0 = (tid & 3) * 16;
      const int srow = tile * 64 + r;
      const float* src = ctxg64 + ((size_t)b * 257 + srow) * 64;
      const bool sv = (srow < nst);
#pragma unroll
      for (int u = 0; u < 8; ++u) {
        const int c = c0 + u * 2;
        float2 v = make_float2(0.f, 0.f);
        if (sv && c < HH) v = *reinterpret_cast<const float2*>(src + c);
        *reinterpret_cast<float2*>(&ct[r * 66 + c]) = v;
      }
    }
    {
      for (int i = tid; i < KK * 64; i += 256) {
        const int k = i >> 6, sl = i & 63;
        const int s = tile * 64 + sl;
        k_l[k * 68 + sl] =
            (s <= TT) ? kqg2[((size_t)b * 16 + k) * 257 + s] : 0.f;
      }
    }
    __syncthreads();

    if (tile * 64 <= tw + 16) {
#pragma unroll 1
      for (int su16 = 0; su16 < 4; ++su16) {
        const int sb = tile * 64 + su16 * 16;
        if (sb > tw + 16) break;

        half4 kf;
#pragma unroll
        for (int i = 0; i < 4; ++i)
          kf[i] = (_Float16)k_l[(4 * lgrp + i) * 68 + su16 * 16 + lrow];

        const f32x4 sc =
            __builtin_amdgcn_mfma_f32_16x16x16f16(kf, qf, zf, 0, 0, 0);

        half4 pa;
#pragma unroll
        for (int r = 0; r < 4; ++r) {
          const int s = sb + 4 * lgrp + r;
          const float p = (s <= tw + lrow + 1) ? __expf(sc[r]) : 0.f;
          su += p;
          pa[r] = (_Float16)p;
        }

        const int vbase = su16 * 16 + 4 * lgrp;
#define PVHT(HT, ACC)                                                     \
  {                                                                       \
    half4 vf;                                                             \
    vf[0] = (_Float16)ct[(vbase + 0) * 66 + lrow + 16 * HT];              \
    vf[1] = (_Float16)ct[(vbase + 1) * 66 + lrow + 16 * HT];              \
    vf[2] = (_Float16)ct[(vbase + 2) * 66 + lrow + 16 * HT];              \
    vf[3] = (_Float16)ct[(vbase + 3) * 66 + lrow + 16 * HT];              \
    ACC = __builtin_amdgcn_mfma_f32_16x16x16f16(pa, vf, ACC, 0, 0, 0);    \
  }
        PVHT(0, acc0) PVHT(1, acc1) PVHT(2, acc2) PVHT(3, acc3)
      }
    }
  }

  su += __shfl_xor(su, 16, 64);
  su += __shfl_xor(su, 32, 64);
  if (lane < 16) su_l[wave * 16 + lane] = su;

#pragma unroll
  for (int r = 0; r < 4; ++r) {
    const int trow = wave * 16 + 4 * lgrp + r;
    o_l[trow * 66 + lrow + 0] = acc0[r];
    o_l[trow * 66 + lrow + 16] = acc1[r];
    o_l[trow * 66 + lrow + 32] = acc2[r];
    o_l[trow * 66 + lrow + 48] = acc3[r];
  }
  __syncthreads();

  {
    const int tl = tid >> 2;
    const int a = tid & 3;
    const float inv = 1.f / su_l[tl];
    const float* orow = &o_l[tl * 66];
    const float* wrow = W_act + a * HH;
    float s0 = 0.f, s1 = 0.f;
#pragma unroll
    for (int h = 0; h < HH; h += 2) {
      s0 = fmaf(orow[h], wrow[h], s0);
      s1 = fmaf(orow[h + 1], wrow[h + 1], s1);
    }
    out[((size_t)(tbase + tl) * BB + b) * AA + a] =
        fmaf(s0 + s1, inv, b_act[a]);
  }
}

extern "C" void kernel_launch(void* const* d_in, const int* in_sizes, int n_in,
                              void* d_out, int out_size, void* d_ws,
                              size_t ws_size, hipStream_t stream) {
  const float* x = (const float*)d_in[0];
  const float* W_in = (const float*)d_in[1];
  const float* b_in = (const float*)d_in[2];
  const float* W_ctx = (const float*)d_in[3];
  const float* b_ctx = (const float*)d_in[4];
  const float* W_key = (const float*)d_in[5];
  const float* b_key = (const float*)d_in[6];
  const float* W_q = (const float*)d_in[7];
  const float* b_q = (const float*)d_in[8];
  const float* fc = (const float*)d_in[9];
  const float* W_act = (const float*)d_in[10];
  const float* b_act = (const float*)d_in[11];
  float* out = (float*)d_out;
  float* ws = (float*)d_ws;

  float* WT = ws;                                   // 128*52
  float* WHT = ws + 8192;                           // 50*52
  float* WK2T = ws + 12288;                         // 50*64
  float* bias2 = ws + 15616;                        // 64
  _Float16* gh = (_Float16*)(ws + 16384);           // 131072*64 f16
  float* hbufT = ws + 16384 + 4194304;              // 50*131072 fl (dead after k1b)
  float* ctxg64 = hbufT;                            // alias; 512*257*64 fl
  float* kqg2 = ctxg64 + (size_t)BB * 257 * 64;     // 512*16*257 fl
  // total ~59 MB

  hipLaunchKernelGGL(k0_prep, dim3(26), dim3(256), 0, stream, W_in, W_ctx,
                     W_key, W_q, b_key, b_q, WT, WHT, WK2T, bias2);
  hipLaunchKernelGGL(k1a, dim3(512), dim3(256), 0, stream, x, WT, b_in, hbufT);
  hipLaunchKernelGGL(k1b, dim3(512), dim3(256), 0, stream, hbufT, WHT, b_ctx,
                     gh);
  hipLaunchKernelGGL(k2_mfma, dim3(32), dim3(64), 0, stream, gh, WK2T, bias2,
                     fc, ctxg64, kqg2);
  hipLaunchKernelGGL(k3_attn, dim3(2048), dim3(256), 0, stream, ctxg64, kqg2,
                     W_act, b_act, out);
}

// Round 17
// 227.387 us; speedup vs baseline: 1.8254x; 1.3661x over previous
//
#include <hip/hip_runtime.h>

#define TT 256
#define BB 512
#define DD 128
#define HH 50
#define KK 5
#define AA 4
#define NROW 131072      // T*B rows
#define GST 56           // g row stride (pass bases 0 and 28, 16B aligned)
#define KQS 260          // kqg row stride (16B-aligned float4 stores at t%4==0)

#define R25(X) X(0) X(1) X(2) X(3) X(4) X(5) X(6) X(7) X(8) X(9) \
  X(10) X(11) X(12) X(13) X(14) X(15) X(16) X(17) X(18) X(19) \
  X(20) X(21) X(22) X(23) X(24)
#define R50(X) X(0) X(1) X(2) X(3) X(4) X(5) X(6) X(7) X(8) X(9) \
  X(10) X(11) X(12) X(13) X(14) X(15) X(16) X(17) X(18) X(19) \
  X(20) X(21) X(22) X(23) X(24) X(25) X(26) X(27) X(28) X(29) \
  X(30) X(31) X(32) X(33) X(34) X(35) X(36) X(37) X(38) X(39) \
  X(40) X(41) X(42) X(43) X(44) X(45) X(46) X(47) X(48) X(49)

typedef _Float16 half4 __attribute__((ext_vector_type(4)));
typedef float f32x4 __attribute__((ext_vector_type(4)));

// ---------------- K0: weight prep ----------------
__global__ void k0_prep(const float* __restrict__ W_in,
                        const float* __restrict__ W_ctx,
                        const float* __restrict__ W_key,
                        const float* __restrict__ W_q,
                        const float* __restrict__ b_key,
                        const float* __restrict__ b_q,
                        float* __restrict__ WT, float* __restrict__ WHT,
                        float* __restrict__ WK2T, float* __restrict__ bias2) {
  int i = blockIdx.x * 256 + threadIdx.x;
  if (i < DD * 52) {
    int j = i / 52, h = i % 52;
    WT[i] = (h < HH) ? W_in[h * DD + j] : 0.f;
  }
  if (i < HH * 52) {
    int j = i / 52, h = i % 52;
    WHT[i] = (h < HH) ? W_ctx[h * (2 * HH) + HH + j] : 0.f;
  }
  if (i < HH * 64) {
    int j = i >> 6, l = i & 63;
    float v = 0.f;
    if (l < HH) v = W_ctx[l * (2 * HH) + j];
    else if (l < HH + KK) v = W_key[(l - HH) * HH + j];
    else if (l < HH + 2 * KK) v = W_q[(l - HH - KK) * HH + j];
    WK2T[i] = v;
  }
  if (i < 64) {
    float bv = 0.f;
    if (i >= HH && i < HH + KK) bv = b_key[i - HH];
    else if (i >= HH + KK && i < HH + 2 * KK) bv = b_q[i - HH - KK];
    bias2[i] = bv;
  }
}

// ---------------- K1a: h = relu(x@W_in^T + b_in), 2 passes x 25 accums ----
__global__ __launch_bounds__(256) void k1a(const float* __restrict__ x,
                                           const float* __restrict__ WT,
                                           const float* __restrict__ b_in,
                                           float* __restrict__ hT) {
  __shared__ float xs[256 * 17];
  const int tid = threadIdx.x;
  const int row = blockIdx.x * 256 + tid;
  const float* __restrict__ xblk = x + (size_t)blockIdx.x * 256 * DD;

#pragma unroll 1
  for (int hp = 0; hp < 2; ++hp) {
    const int hb = hp * 25;
#define DECLA(i) float a##i = b_in[hb + i];
    R25(DECLA)

#pragma unroll 1
    for (int jb = 0; jb < 8; ++jb) {
      __syncthreads();
#pragma unroll
      for (int u = 0; u < 4; ++u) {
        const int f = tid + u * 256;
        const int r = f >> 2, c4 = f & 3;
        const float4 v = *reinterpret_cast<const float4*>(
            xblk + (size_t)r * DD + jb * 16 + c4 * 4);
        float* d = &xs[r * 17 + c4 * 4];
        d[0] = v.x; d[1] = v.y; d[2] = v.z; d[3] = v.w;
      }
      __syncthreads();
      const float* __restrict__ xrow = &xs[tid * 17];
#pragma unroll
      for (int cc = 0; cc < 16; cc += 4) {
        const int j = jb * 16 + cc;
        const float xv0 = xrow[cc + 0];
        const float xv1 = xrow[cc + 1];
        const float xv2 = xrow[cc + 2];
        const float xv3 = xrow[cc + 3];
        const float* __restrict__ w0 = WT + (j + 0) * 52 + hb;
        const float* __restrict__ w1 = WT + (j + 1) * 52 + hb;
        const float* __restrict__ w2 = WT + (j + 2) * 52 + hb;
        const float* __restrict__ w3 = WT + (j + 3) * 52 + hb;
#define FMA25(i)                  \
  a##i = fmaf(xv0, w0[i], a##i);  \
  a##i = fmaf(xv1, w1[i], a##i);  \
  a##i = fmaf(xv2, w2[i], a##i);  \
  a##i = fmaf(xv3, w3[i], a##i);
        R25(FMA25)
      }
    }

#define STA(i) hT[(size_t)(hb + i) * NROW + row] = fmaxf(a##i, 0.f);
    R25(STA)
  }
}

// ---------------- K1b: g = h @ Wh^T + b_ctx, 2 passes x 25 accums ----------
// h read coalesced from hT[h][row]; g written per-chain contiguous:
// g[(b*TT + t)*GST + slot] (row = t*BB + b).
__global__ __launch_bounds__(256) void k1b(const float* __restrict__ hT,
                                           const float* __restrict__ WHT,
                                           const float* __restrict__ b_ctx,
                                           float* __restrict__ g) {
  const int row = blockIdx.x * 256 + threadIdx.x;
  const int b = row & (BB - 1);
  const int t = row >> 9;

#pragma unroll 1
  for (int gp = 0; gp < 2; ++gp) {
    const int gb = gp * 25;
#define DECLG(i) float a##i = b_ctx[gb + i];
    R25(DECLG)

#pragma unroll 5
    for (int s = 0; s < HH; ++s) {
      const float hv = hT[(size_t)s * NROW + row];
      const float* __restrict__ wh = WHT + s * 52 + gb;
#define GFMA(i) a##i = fmaf(hv, wh[i], a##i);
      R25(GFMA)
    }

    float* __restrict__ gr = g + ((size_t)b * TT + t) * GST + gp * 28;
    *reinterpret_cast<float4*>(gr + 0) = make_float4(a0, a1, a2, a3);
    *reinterpret_cast<float4*>(gr + 4) = make_float4(a4, a5, a6, a7);
    *reinterpret_cast<float4*>(gr + 8) = make_float4(a8, a9, a10, a11);
    *reinterpret_cast<float4*>(gr + 12) = make_float4(a12, a13, a14, a15);
    *reinterpret_cast<float4*>(gr + 16) = make_float4(a16, a17, a18, a19);
    *reinterpret_cast<float4*>(gr + 20) = make_float4(a20, a21, a22, a23);
    gr[24] = a24;
  }
}

// ---------------- K2: per-batch recurrence (512 blocks x 1 wave) -----------
// R12 scalar core (102us measured) + register-batched kq egress: lanes 50-59
// hold 4 step-values in named regs, ONE aligned float4 store per 4 steps
// (kqg[b][10][260]: rows 0-4 key@s, rows 5-9 q@t; k3 reads q at t+1).
// Replaces 40 scattered dwords/4-steps with 10 vector stores.
__global__ __launch_bounds__(64) void k2_rec(
    const float* __restrict__ g, const float* __restrict__ WK2T,
    const float* __restrict__ bias2, const float* __restrict__ first_context,
    float* __restrict__ ctxg, float* __restrict__ kqg) {
  __shared__ __align__(16) float c_lds[64];
  const int b = blockIdx.x;
  const int lane = threadIdx.x;

#define WDECL(j)                            \
  float w##j = WK2T[(j) * 64 + lane];       \
  asm volatile("" : "+v"(w##j));
  R50(WDECL)
  const float wz = 0.f;
  const float bias = bias2[lane];

  const float c0v = (lane < HH) ? first_context[lane] : 0.f;
  c_lds[lane] = (lane < HH) ? c0v : 0.f;  // [50..63] stay 0 forever
  if (lane < HH) ctxg[((size_t)b * 257 + 0) * HH + lane] = c0v;

  const int gslot = lane + (lane >= 25 ? 3 : 0);  // k1b's stride-56 layout
  const float* __restrict__ gbp = g + (size_t)b * TT * GST + gslot;
  float gq0 = gbp[0 * GST];
  float gq1 = gbp[1 * GST];
  float gq2 = gbp[2 * GST];
  float gq3 = gbp[3 * GST];

  const bool iskq = (lane >= HH && lane < HH + 2 * KK);
  float* __restrict__ kqrow =
      kqg + ((size_t)b * 10 + (iskq ? lane - HH : 0)) * KQS;

#define KQ(J, wa, wb, wc, wd)                                            \
  {                                                                      \
    const float4 cq = *reinterpret_cast<const float4*>(&c_lds[J]);       \
    acc0 = fmaf(wa, cq.x, acc0);                                         \
    acc1 = fmaf(wb, cq.y, acc1);                                         \
    acc2 = fmaf(wc, cq.z, acc2);                                         \
    acc3 = fmaf(wd, cq.w, acc3);                                         \
  }
#define DOT50R                                                           \
  float acc0 = 0.f, acc1 = 0.f, acc2 = 0.f, acc3 = 0.f;                  \
  KQ(0, w0, w1, w2, w3) KQ(4, w4, w5, w6, w7)                            \
  KQ(8, w8, w9, w10, w11) KQ(12, w12, w13, w14, w15)                     \
  KQ(16, w16, w17, w18, w19) KQ(20, w20, w21, w22, w23)                  \
  KQ(24, w24, w25, w26, w27) KQ(28, w28, w29, w30, w31)                  \
  KQ(32, w32, w33, w34, w35) KQ(36, w36, w37, w38, w39)                  \
  KQ(40, w40, w41, w42, w43) KQ(44, w44, w45, w46, w47)                  \
  KQ(48, w48, w49, wz, wz)                                               \
  const float acc = (acc0 + acc1) + (acc2 + acc3);

#define BODY(RR, GQ)                                                     \
  {                                                                      \
    const int t = tg4 + RR;                                              \
    DOT50R                                                               \
    kqa##RR = acc + bias;                                                \
    const float cn = fmaxf(acc + GQ, 0.f);                               \
    GQ = gbp[(size_t)min(t + 4, TT - 1) * GST]; /* uncond, direct def */ \
    if (lane < HH) {                                                     \
      ctxg[((size_t)b * 257 + (t + 1)) * HH + lane] = cn;                \
      c_lds[lane] = cn;  /* in-wave DS order: visible next body */       \
    }                                                                    \
  }

#pragma unroll 1
  for (int tg4 = 0; tg4 < TT; tg4 += 4) {
    float kqa0, kqa1, kqa2, kqa3;
    BODY(0, gq0) BODY(1, gq1) BODY(2, gq2) BODY(3, gq3)
    if (iskq) {
      *reinterpret_cast<float4*>(kqrow + tg4) =
          make_float4(kqa0, kqa1, kqa2, kqa3);
    }
  }

  {  // tail: key/q of c_TT at index TT (=256)
    DOT50R
    if (iskq) kqrow[TT] = acc + bias;
  }
}

// ---------------- K3: MFMA flash attention, LDS-staged ---------------------
// ctx[b][257][50]; keys kqg[b][k][s] (k 0-4, stride 260); q for output t:
// kqg[b][5+k][t+1]. k_l is 16 rows with rows 5-15 hard-zeroed (the QK
// A-fragment reads rows 0-15; R9-R15 read past an 8-row array -> NaN risk).
__global__ __launch_bounds__(256, 4) void k3_attn(
    const float* __restrict__ ctxg, const float* __restrict__ kqg,
    const float* __restrict__ W_act, const float* __restrict__ b_act,
    float* __restrict__ out) {
  __shared__ __align__(16) float ct[64 * 66];    // [s_local][h]
  __shared__ __align__(16) float k_l[16 * 68];   // [k][s_local], rows 5-15=0
  __shared__ __align__(16) float o_l[64 * 66];   // [t_local][h]
  __shared__ float su_l[64];

  const int tid = threadIdx.x;
  const int bid = blockIdx.x;
  const int chunk = 3 - (bid >> 9);  // heavy-first
  const int b = bid & 511;
  const int tbase = chunk * 64;
  const int nst = min(tbase + 66, 257);
  const int ntiles = (nst + 63) >> 6;
  const int wave = tid >> 6;
  const int lane = tid & 63;
  const int lrow = lane & 15;
  const int lgrp = lane >> 4;
  const int tw = tbase + wave * 16;

  for (int i = tid; i < 11 * 68; i += 256) k_l[5 * 68 + i] = 0.f;

  half4 qf;
#pragma unroll
  for (int i = 0; i < 4; ++i) {
    const int k = 4 * lgrp + i;
    qf[i] = (_Float16)((k < KK)
                           ? kqg[((size_t)b * 10 + 5 + k) * KQS + tw + lrow + 1]
                           : 0.f);
  }

  const f32x4 zf = {0.f, 0.f, 0.f, 0.f};
  f32x4 acc0 = zf, acc1 = zf, acc2 = zf, acc3 = zf;
  float su = 0.f;

#pragma unroll 1
  for (int tile = 0; tile < ntiles; ++tile) {
    __syncthreads();
    {
      const int r = tid >> 2;
      const int c0 = (tid & 3) * 16;
      const int srow = tile * 64 + r;
      const float* src = ctxg + ((size_t)b * 257 + srow) * HH;
      const bool sv = (srow < nst);
#pragma unroll
      for (int u = 0; u < 8; ++u) {
        const int c = c0 + u * 2;
        float2 v = make_float2(0.f, 0.f);
        if (sv && c < HH) v = *reinterpret_cast<const float2*>(src + c);
        *reinterpret_cast<float2*>(&ct[r * 66 + c]) = v;
      }
    }
    {
      for (int i = tid; i < KK * 64; i += 256) {
        const int k = i >> 6, sl = i & 63;
        const int s = tile * 64 + sl;
        k_l[k * 68 + sl] =
            (s <= TT) ? kqg[((size_t)b * 10 + k) * KQS + s] : 0.f;
      }
    }
    __syncthreads();

    if (tile * 64 <= tw + 16) {
#pragma unroll 1
      for (int su16 = 0; su16 < 4; ++su16) {
        const int sb = tile * 64 + su16 * 16;
        if (sb > tw + 16) break;

        half4 kf;
#pragma unroll
        for (int i = 0; i < 4; ++i)
          kf[i] = (_Float16)k_l[(4 * lgrp + i) * 68 + su16 * 16 + lrow];

        const f32x4 sc =
            __builtin_amdgcn_mfma_f32_16x16x16f16(kf, qf, zf, 0, 0, 0);

        half4 pa;
#pragma unroll
        for (int r = 0; r < 4; ++r) {
          const int s = sb + 4 * lgrp + r;
          const float p = (s <= tw + lrow + 1) ? __expf(sc[r]) : 0.f;
          su += p;
          pa[r] = (_Float16)p;
        }

        const int vbase = su16 * 16 + 4 * lgrp;
#define PVHT(HT, ACC)                                                     \
  {                                                                       \
    half4 vf;                                                             \
    vf[0] = (_Float16)ct[(vbase + 0) * 66 + lrow + 16 * HT];              \
    vf[1] = (_Float16)ct[(vbase + 1) * 66 + lrow + 16 * HT];              \
    vf[2] = (_Float16)ct[(vbase + 2) * 66 + lrow + 16 * HT];              \
    vf[3] = (_Float16)ct[(vbase + 3) * 66 + lrow + 16 * HT];              \
    ACC = __builtin_amdgcn_mfma_f32_16x16x16f16(pa, vf, ACC, 0, 0, 0);    \
  }
        PVHT(0, acc0) PVHT(1, acc1) PVHT(2, acc2) PVHT(3, acc3)
      }
    }
  }

  su += __shfl_xor(su, 16, 64);
  su += __shfl_xor(su, 32, 64);
  if (lane < 16) su_l[wave * 16 + lane] = su;

#pragma unroll
  for (int r = 0; r < 4; ++r) {
    const int trow = wave * 16 + 4 * lgrp + r;
    o_l[trow * 66 + lrow + 0] = acc0[r];
    o_l[trow * 66 + lrow + 16] = acc1[r];
    o_l[trow * 66 + lrow + 32] = acc2[r];
    o_l[trow * 66 + lrow + 48] = acc3[r];
  }
  __syncthreads();

  {
    const int tl = tid >> 2;
    const int a = tid & 3;
    const float inv = 1.f / su_l[tl];
    const float* orow = &o_l[tl * 66];
    const float* wrow = W_act + a * HH;
    float s0 = 0.f, s1 = 0.f;
#pragma unroll
    for (int h = 0; h < HH; h += 2) {
      s0 = fmaf(orow[h], wrow[h], s0);
      s1 = fmaf(orow[h + 1], wrow[h + 1], s1);
    }
    out[((size_t)(tbase + tl) * BB + b) * AA + a] =
        fmaf(s0 + s1, inv, b_act[a]);
  }
}

extern "C" void kernel_launch(void* const* d_in, const int* in_sizes, int n_in,
                              void* d_out, int out_size, void* d_ws,
                              size_t ws_size, hipStream_t stream) {
  const float* x = (const float*)d_in[0];
  const float* W_in = (const float*)d_in[1];
  const float* b_in = (const float*)d_in[2];
  const float* W_ctx = (const float*)d_in[3];
  const float* b_ctx = (const float*)d_in[4];
  const float* W_key = (const float*)d_in[5];
  const float* b_key = (const float*)d_in[6];
  const float* W_q = (const float*)d_in[7];
  const float* b_q = (const float*)d_in[8];
  const float* fc = (const float*)d_in[9];
  const float* W_act = (const float*)d_in[10];
  const float* b_act = (const float*)d_in[11];
  float* out = (float*)d_out;
  float* ws = (float*)d_ws;

  float* WT = ws;                                  // 128*52
  float* WHT = ws + 8192;                          // 50*52
  float* WK2T = ws + 12288;                        // 50*64
  float* bias2 = ws + 15616;                       // 64
  float* g = ws + 16384;                           // 131072*56 (+64 pad)
  float* hbufT = g + (size_t)NROW * GST + 64;      // 50*131072 (dead after k1b)
  float* ctxg = hbufT;                             // alias; 512*257*50
  float* kqg = hbufT + (size_t)BB * 257 * HH;      // 512*10*260
  // total ~61 MB

  hipLaunchKernelGGL(k0_prep, dim3(26), dim3(256), 0, stream, W_in, W_ctx,
                     W_key, W_q, b_key, b_q, WT, WHT, WK2T, bias2);
  hipLaunchKernelGGL(k1a, dim3(512), dim3(256), 0, stream, x, WT, b_in, hbufT);
  hipLaunchKernelGGL(k1b, dim3(512), dim3(256), 0, stream, hbufT, WHT, b_ctx,
                     g);
  hipLaunchKernelGGL(k2_rec, dim3(512), dim3(64), 0, stream, g, WK2T, bias2,
                     fc, ctxg, kqg);
  hipLaunchKernelGGL(k3_attn, dim3(2048), dim3(256), 0, stream, ctxg, kqg,
                     W_act, b_act, out);
}

// Round 18
// 150.844 us; speedup vs baseline: 2.7517x; 1.5074x over previous
//
#include <hip/hip_runtime.h>

#define TT 256
#define BB 512
#define DD 128
#define HH 50
#define KK 5
#define AA 4
#define NROW 131072
#define GST 52           // g row stride (16B-aligned float4 slots)
#define KQS 260          // kqg row stride

#define R50(X) X(0) X(1) X(2) X(3) X(4) X(5) X(6) X(7) X(8) X(9) \
  X(10) X(11) X(12) X(13) X(14) X(15) X(16) X(17) X(18) X(19) \
  X(20) X(21) X(22) X(23) X(24) X(25) X(26) X(27) X(28) X(29) \
  X(30) X(31) X(32) X(33) X(34) X(35) X(36) X(37) X(38) X(39) \
  X(40) X(41) X(42) X(43) X(44) X(45) X(46) X(47) X(48) X(49)

typedef _Float16 half4 __attribute__((ext_vector_type(4)));
typedef float f32x4 __attribute__((ext_vector_type(4)));

// ---------------- K0: weight prep ----------------
__global__ void k0_prep(const float* __restrict__ W_in,
                        const float* __restrict__ W_ctx,
                        const float* __restrict__ W_key,
                        const float* __restrict__ W_q,
                        const float* __restrict__ b_key,
                        const float* __restrict__ b_q,
                        float* __restrict__ WHT,
                        float* __restrict__ WK2T, float* __restrict__ bias2) {
  int i = blockIdx.x * 256 + threadIdx.x;
  if (i < HH * 52) {
    int j = i / 52, h = i % 52;
    WHT[i] = (h < HH) ? W_ctx[h * (2 * HH) + HH + j] : 0.f;
  }
  if (i < HH * 64) {
    int j = i >> 6, l = i & 63;
    float v = 0.f;
    if (l < HH) v = W_ctx[l * (2 * HH) + j];
    else if (l < HH + KK) v = W_key[(l - HH) * HH + j];
    else if (l < HH + 2 * KK) v = W_q[(l - HH - KK) * HH + j];
    WK2T[i] = v;
  }
  if (i < 64) {
    float bv = 0.f;
    if (i >= HH && i < HH + KK) bv = b_key[i - HH];
    else if (i >= HH + KK && i < HH + 2 * KK) bv = b_q[i - HH - KK];
    bias2[i] = bv;
  }
}

// ---------------- K1 (MFMA, fused): g = relu(x@W_in^T+b_in)@Wh^T + b_ctx ---
// Per 16-row tile: pass1 h^T = W_in(A) x^T(B), K=128 (32 MFMA); bias+relu
// in-lane; D-frag==B-frag identity feeds pass2 g^T = Wh(A) h^T(B), K=64
// zero-padded (16 MFMA). No LDS, no barriers, no intermediate buffer.
// g stored in k2's chain layout g[(b*TT+t)*GST + gg].
__global__ __launch_bounds__(256, 2) void k1_mfma(
    const float* __restrict__ x, const float* __restrict__ W_in,
    const float* __restrict__ WHT, const float* __restrict__ b_in,
    const float* __restrict__ b_ctx, float* __restrict__ g) {
  const int lane = threadIdx.x & 63;
  const int wave = threadIdx.x >> 6;
  const int lrow = lane & 15, lgrp = lane >> 4;

  // pass-1 A-frags: A[hh][j] = W_in[16m+lrow][16kk+4lgrp+i], hh>=50 -> 0
#define WA1D(m, kk)                                                     \
  half4 wa1_##m##_##kk;                                                 \
  {                                                                     \
    const int hh = 16 * (m) + lrow;                                     \
    const int j0 = 16 * (kk) + 4 * lgrp;                                \
    const bool v = (hh < HH);                                           \
    const float* p = W_in + (size_t)(v ? hh : 0) * DD + j0;             \
    wa1_##m##_##kk[0] = (_Float16)(v ? p[0] : 0.f);                     \
    wa1_##m##_##kk[1] = (_Float16)(v ? p[1] : 0.f);                     \
    wa1_##m##_##kk[2] = (_Float16)(v ? p[2] : 0.f);                     \
    wa1_##m##_##kk[3] = (_Float16)(v ? p[3] : 0.f);                     \
  }
  WA1D(0, 0) WA1D(0, 1) WA1D(0, 2) WA1D(0, 3)
  WA1D(0, 4) WA1D(0, 5) WA1D(0, 6) WA1D(0, 7)
  WA1D(1, 0) WA1D(1, 1) WA1D(1, 2) WA1D(1, 3)
  WA1D(1, 4) WA1D(1, 5) WA1D(1, 6) WA1D(1, 7)
  WA1D(2, 0) WA1D(2, 1) WA1D(2, 2) WA1D(2, 3)
  WA1D(2, 4) WA1D(2, 5) WA1D(2, 6) WA1D(2, 7)
  WA1D(3, 0) WA1D(3, 1) WA1D(3, 2) WA1D(3, 3)
  WA1D(3, 4) WA1D(3, 5) WA1D(3, 6) WA1D(3, 7)

  // pass-2 A-frags: A[gg][hh] = Wh[16m+lrow][16kk+4lgrp+i] = WHT[hh*52+gg]
#define WA2D(m, kk)                                                     \
  half4 wa2_##m##_##kk;                                                 \
  {                                                                     \
    const int gg = 16 * (m) + lrow;                                     \
    const int h0 = 16 * (kk) + 4 * lgrp;                                \
    wa2_##m##_##kk[0] = (_Float16)((gg < HH && h0 + 0 < HH) ? WHT[(h0 + 0) * 52 + gg] : 0.f); \
    wa2_##m##_##kk[1] = (_Float16)((gg < HH && h0 + 1 < HH) ? WHT[(h0 + 1) * 52 + gg] : 0.f); \
    wa2_##m##_##kk[2] = (_Float16)((gg < HH && h0 + 2 < HH) ? WHT[(h0 + 2) * 52 + gg] : 0.f); \
    wa2_##m##_##kk[3] = (_Float16)((gg < HH && h0 + 3 < HH) ? WHT[(h0 + 3) * 52 + gg] : 0.f); \
  }
  WA2D(0, 0) WA2D(0, 1) WA2D(0, 2) WA2D(0, 3)
  WA2D(1, 0) WA2D(1, 1) WA2D(1, 2) WA2D(1, 3)
  WA2D(2, 0) WA2D(2, 1) WA2D(2, 2) WA2D(2, 3)
  WA2D(3, 0) WA2D(3, 1) WA2D(3, 2) WA2D(3, 3)

  // biases: index 16m + 4lgrp + r, guarded
#define BDEF(m, r)                                                      \
  const float bin_##m##_##r =                                           \
      (16 * (m) + 4 * lgrp + (r) < HH) ? b_in[16 * (m) + 4 * lgrp + (r)] : 0.f; \
  const float bct_##m##_##r =                                           \
      (16 * (m) + 4 * lgrp + (r) < HH) ? b_ctx[16 * (m) + 4 * lgrp + (r)] : 0.f;
  BDEF(0, 0) BDEF(0, 1) BDEF(0, 2) BDEF(0, 3)
  BDEF(1, 0) BDEF(1, 1) BDEF(1, 2) BDEF(1, 3)
  BDEF(2, 0) BDEF(2, 1) BDEF(2, 2) BDEF(2, 3)
  BDEF(3, 0) BDEF(3, 1) BDEF(3, 2) BDEF(3, 3)

  const f32x4 zf = {0.f, 0.f, 0.f, 0.f};

#pragma unroll 1
  for (int it = 0; it < 4; ++it) {
    const int tile = (blockIdx.x * 4 + wave) * 4 + it;
    const int row = tile * 16 + lrow;
    const float* __restrict__ xr = x + (size_t)row * DD + 4 * lgrp;

#define XLD(kk)                                                         \
  half4 xb##kk;                                                         \
  {                                                                     \
    const float4 xv = *reinterpret_cast<const float4*>(xr + 16 * kk);   \
    xb##kk[0] = (_Float16)xv.x;                                         \
    xb##kk[1] = (_Float16)xv.y;                                         \
    xb##kk[2] = (_Float16)xv.z;                                         \
    xb##kk[3] = (_Float16)xv.w;                                         \
  }
    XLD(0) XLD(1) XLD(2) XLD(3) XLD(4) XLD(5) XLD(6) XLD(7)

    f32x4 d10 = zf, d11 = zf, d12 = zf, d13 = zf;
#define MM1(kk)                                                              \
  d10 = __builtin_amdgcn_mfma_f32_16x16x16f16(wa1_0_##kk, xb##kk, d10, 0, 0, 0); \
  d11 = __builtin_amdgcn_mfma_f32_16x16x16f16(wa1_1_##kk, xb##kk, d11, 0, 0, 0); \
  d12 = __builtin_amdgcn_mfma_f32_16x16x16f16(wa1_2_##kk, xb##kk, d12, 0, 0, 0); \
  d13 = __builtin_amdgcn_mfma_f32_16x16x16f16(wa1_3_##kk, xb##kk, d13, 0, 0, 0);
    MM1(0) MM1(1) MM1(2) MM1(3) MM1(4) MM1(5) MM1(6) MM1(7)

#define HBD(k)                                                    \
  half4 hb##k;                                                    \
  hb##k[0] = (_Float16)fmaxf(d1##k[0] + bin_##k##_0, 0.f);        \
  hb##k[1] = (_Float16)fmaxf(d1##k[1] + bin_##k##_1, 0.f);        \
  hb##k[2] = (_Float16)fmaxf(d1##k[2] + bin_##k##_2, 0.f);        \
  hb##k[3] = (_Float16)fmaxf(d1##k[3] + bin_##k##_3, 0.f);
    HBD(0) HBD(1) HBD(2) HBD(3)

    f32x4 d20 = zf, d21 = zf, d22 = zf, d23 = zf;
#define MM2(kk)                                                              \
  d20 = __builtin_amdgcn_mfma_f32_16x16x16f16(wa2_0_##kk, hb##kk, d20, 0, 0, 0); \
  d21 = __builtin_amdgcn_mfma_f32_16x16x16f16(wa2_1_##kk, hb##kk, d21, 0, 0, 0); \
  d22 = __builtin_amdgcn_mfma_f32_16x16x16f16(wa2_2_##kk, hb##kk, d22, 0, 0, 0); \
  d23 = __builtin_amdgcn_mfma_f32_16x16x16f16(wa2_3_##kk, hb##kk, d23, 0, 0, 0);
    MM2(0) MM2(1) MM2(2) MM2(3)

    // store g^T[gg][row] -> g[(b*TT + t)*GST + gg]; rows of a tile share t
    float* __restrict__ gr =
        g + ((size_t)(row & (BB - 1)) * TT + (row >> 9)) * GST;
    *reinterpret_cast<float4*>(gr + 4 * lgrp) =
        make_float4(d20[0] + bct_0_0, d20[1] + bct_0_1, d20[2] + bct_0_2,
                    d20[3] + bct_0_3);
    *reinterpret_cast<float4*>(gr + 16 + 4 * lgrp) =
        make_float4(d21[0] + bct_1_0, d21[1] + bct_1_1, d21[2] + bct_1_2,
                    d21[3] + bct_1_3);
    *reinterpret_cast<float4*>(gr + 32 + 4 * lgrp) =
        make_float4(d22[0] + bct_2_0, d22[1] + bct_2_1, d22[2] + bct_2_2,
                    d22[3] + bct_2_3);
    if (lgrp == 0) {  // gg 48,49 valid; 50,51 stored as 0
      *reinterpret_cast<float4*>(gr + 48) =
          make_float4(d23[0] + bct_3_0, d23[1] + bct_3_1, 0.f, 0.f);
    }
  }
}

// ---------------- K2: per-batch recurrence (512 blocks x 1 wave) -----------
// R12 scalar core + register-batched kq egress (R17, measured 80.7us).
// g layout: g[(b*TT + t)*GST + gg], gslot = lane (linear, GST=52).
__global__ __launch_bounds__(64) void k2_rec(
    const float* __restrict__ g, const float* __restrict__ WK2T,
    const float* __restrict__ bias2, const float* __restrict__ first_context,
    float* __restrict__ ctxg, float* __restrict__ kqg) {
  __shared__ __align__(16) float c_lds[64];
  const int b = blockIdx.x;
  const int lane = threadIdx.x;

#define WDECL(j)                            \
  float w##j = WK2T[(j) * 64 + lane];       \
  asm volatile("" : "+v"(w##j));
  R50(WDECL)
  const float wz = 0.f;
  const float bias = bias2[lane];

  const float c0v = (lane < HH) ? first_context[lane] : 0.f;
  c_lds[lane] = (lane < HH) ? c0v : 0.f;
  if (lane < HH) ctxg[((size_t)b * 257 + 0) * HH + lane] = c0v;

  const int gslot = (lane < GST) ? lane : (GST - 1);
  const float* __restrict__ gbp = g + (size_t)b * TT * GST + gslot;
  float gq0 = gbp[0 * GST];
  float gq1 = gbp[1 * GST];
  float gq2 = gbp[2 * GST];
  float gq3 = gbp[3 * GST];

  const bool iskq = (lane >= HH && lane < HH + 2 * KK);
  float* __restrict__ kqrow =
      kqg + ((size_t)b * 10 + (iskq ? lane - HH : 0)) * KQS;

#define KQ(J, wa, wb, wc, wd)                                            \
  {                                                                      \
    const float4 cq = *reinterpret_cast<const float4*>(&c_lds[J]);       \
    acc0 = fmaf(wa, cq.x, acc0);                                         \
    acc1 = fmaf(wb, cq.y, acc1);                                         \
    acc2 = fmaf(wc, cq.z, acc2);                                         \
    acc3 = fmaf(wd, cq.w, acc3);                                         \
  }
#define DOT50R                                                           \
  float acc0 = 0.f, acc1 = 0.f, acc2 = 0.f, acc3 = 0.f;                  \
  KQ(0, w0, w1, w2, w3) KQ(4, w4, w5, w6, w7)                            \
  KQ(8, w8, w9, w10, w11) KQ(12, w12, w13, w14, w15)                     \
  KQ(16, w16, w17, w18, w19) KQ(20, w20, w21, w22, w23)                  \
  KQ(24, w24, w25, w26, w27) KQ(28, w28, w29, w30, w31)                  \
  KQ(32, w32, w33, w34, w35) KQ(36, w36, w37, w38, w39)                  \
  KQ(40, w40, w41, w42, w43) KQ(44, w44, w45, w46, w47)                  \
  KQ(48, w48, w49, wz, wz)                                               \
  const float acc = (acc0 + acc1) + (acc2 + acc3);

#define BODY(RR, GQ)                                                     \
  {                                                                      \
    const int t = tg4 + RR;                                              \
    DOT50R                                                               \
    kqa##RR = acc + bias;                                                \
    const float cn = fmaxf(acc + GQ, 0.f);                               \
    GQ = gbp[(size_t)min(t + 4, TT - 1) * GST];                          \
    if (lane < HH) {                                                     \
      ctxg[((size_t)b * 257 + (t + 1)) * HH + lane] = cn;                \
      c_lds[lane] = cn;                                                  \
    }                                                                    \
  }

#pragma unroll 1
  for (int tg4 = 0; tg4 < TT; tg4 += 4) {
    float kqa0, kqa1, kqa2, kqa3;
    BODY(0, gq0) BODY(1, gq1) BODY(2, gq2) BODY(3, gq3)
    if (iskq) {
      *reinterpret_cast<float4*>(kqrow + tg4) =
          make_float4(kqa0, kqa1, kqa2, kqa3);
    }
  }

  {  // tail: key/q of c_TT at index TT
    DOT50R
    if (iskq) kqrow[TT] = acc + bias;
  }
}

// ---------------- K3: MFMA flash attention, LDS-staged (R17, passing) ------
__global__ __launch_bounds__(256, 4) void k3_attn(
    const float* __restrict__ ctxg, const float* __restrict__ kqg,
    const float* __restrict__ W_act, const float* __restrict__ b_act,
    float* __restrict__ out) {
  __shared__ __align__(16) float ct[64 * 66];
  __shared__ __align__(16) float k_l[16 * 68];  // rows 5-15 hard-zeroed
  __shared__ __align__(16) float o_l[64 * 66];
  __shared__ float su_l[64];

  const int tid = threadIdx.x;
  const int bid = blockIdx.x;
  const int chunk = 3 - (bid >> 9);
  const int b = bid & 511;
  const int tbase = chunk * 64;
  const int nst = min(tbase + 66, 257);
  const int ntiles = (nst + 63) >> 6;
  const int wave = tid >> 6;
  const int lane = tid & 63;
  const int lrow = lane & 15;
  const int lgrp = lane >> 4;
  const int tw = tbase + wave * 16;

  for (int i = tid; i < 11 * 68; i += 256) k_l[5 * 68 + i] = 0.f;

  half4 qf;
#pragma unroll
  for (int i = 0; i < 4; ++i) {
    const int k = 4 * lgrp + i;
    qf[i] = (_Float16)((k < KK)
                           ? kqg[((size_t)b * 10 + 5 + k) * KQS + tw + lrow + 1]
                           : 0.f);
  }

  const f32x4 zf = {0.f, 0.f, 0.f, 0.f};
  f32x4 acc0 = zf, acc1 = zf, acc2 = zf, acc3 = zf;
  float su = 0.f;

#pragma unroll 1
  for (int tile = 0; tile < ntiles; ++tile) {
    __syncthreads();
    {
      const int r = tid >> 2;
      const int c0 = (tid & 3) * 16;
      const int srow = tile * 64 + r;
      const float* src = ctxg + ((size_t)b * 257 + srow) * HH;
      const bool sv = (srow < nst);
#pragma unroll
      for (int u = 0; u < 8; ++u) {
        const int c = c0 + u * 2;
        float2 v = make_float2(0.f, 0.f);
        if (sv && c < HH) v = *reinterpret_cast<const float2*>(src + c);
        *reinterpret_cast<float2*>(&ct[r * 66 + c]) = v;
      }
    }
    {
      for (int i = tid; i < KK * 64; i += 256) {
        const int k = i >> 6, sl = i & 63;
        const int s = tile * 64 + sl;
        k_l[k * 68 + sl] =
            (s <= TT) ? kqg[((size_t)b * 10 + k) * KQS + s] : 0.f;
      }
    }
    __syncthreads();

    if (tile * 64 <= tw + 16) {
#pragma unroll 1
      for (int su16 = 0; su16 < 4; ++su16) {
        const int sb = tile * 64 + su16 * 16;
        if (sb > tw + 16) break;

        half4 kf;
#pragma unroll
        for (int i = 0; i < 4; ++i)
          kf[i] = (_Float16)k_l[(4 * lgrp + i) * 68 + su16 * 16 + lrow];

        const f32x4 sc =
            __builtin_amdgcn_mfma_f32_16x16x16f16(kf, qf, zf, 0, 0, 0);

        half4 pa;
#pragma unroll
        for (int r = 0; r < 4; ++r) {
          const int s = sb + 4 * lgrp + r;
          const float p = (s <= tw + lrow + 1) ? __expf(sc[r]) : 0.f;
          su += p;
          pa[r] = (_Float16)p;
        }

        const int vbase = su16 * 16 + 4 * lgrp;
#define PVHT(HT, ACC)                                                     \
  {                                                                       \
    half4 vf;                                                             \
    vf[0] = (_Float16)ct[(vbase + 0) * 66 + lrow + 16 * HT];              \
    vf[1] = (_Float16)ct[(vbase + 1) * 66 + lrow + 16 * HT];              \
    vf[2] = (_Float16)ct[(vbase + 2) * 66 + lrow + 16 * HT];              \
    vf[3] = (_Float16)ct[(vbase + 3) * 66 + lrow + 16 * HT];              \
    ACC = __builtin_amdgcn_mfma_f32_16x16x16f16(pa, vf, ACC, 0, 0, 0);    \
  }
        PVHT(0, acc0) PVHT(1, acc1) PVHT(2, acc2) PVHT(3, acc3)
      }
    }
  }

  su += __shfl_xor(su, 16, 64);
  su += __shfl_xor(su, 32, 64);
  if (lane < 16) su_l[wave * 16 + lane] = su;

#pragma unroll
  for (int r = 0; r < 4; ++r) {
    const int trow = wave * 16 + 4 * lgrp + r;
    o_l[trow * 66 + lrow + 0] = acc0[r];
    o_l[trow * 66 + lrow + 16] = acc1[r];
    o_l[trow * 66 + lrow + 32] = acc2[r];
    o_l[trow * 66 + lrow + 48] = acc3[r];
  }
  __syncthreads();

  {
    const int tl = tid >> 2;
    const int a = tid & 3;
    const float inv = 1.f / su_l[tl];
    const float* orow = &o_l[tl * 66];
    const float* wrow = W_act + a * HH;
    float s0 = 0.f, s1 = 0.f;
#pragma unroll
    for (int h = 0; h < HH; h += 2) {
      s0 = fmaf(orow[h], wrow[h], s0);
      s1 = fmaf(orow[h + 1], wrow[h + 1], s1);
    }
    out[((size_t)(tbase + tl) * BB + b) * AA + a] =
        fmaf(s0 + s1, inv, b_act[a]);
  }
}

extern "C" void kernel_launch(void* const* d_in, const int* in_sizes, int n_in,
                              void* d_out, int out_size, void* d_ws,
                              size_t ws_size, hipStream_t stream) {
  const float* x = (const float*)d_in[0];
  const float* W_in = (const float*)d_in[1];
  const float* b_in = (const float*)d_in[2];
  const float* W_ctx = (const float*)d_in[3];
  const float* b_ctx = (const float*)d_in[4];
  const float* W_key = (const float*)d_in[5];
  const float* b_key = (const float*)d_in[6];
  const float* W_q = (const float*)d_in[7];
  const float* b_q = (const float*)d_in[8];
  const float* fc = (const float*)d_in[9];
  const float* W_act = (const float*)d_in[10];
  const float* b_act = (const float*)d_in[11];
  float* out = (float*)d_out;
  float* ws = (float*)d_ws;

  float* WHT = ws;                                 // 50*52
  float* WK2T = ws + 4096;                         // 50*64
  float* bias2 = ws + 8128;                        // 64
  float* g = ws + 8192;                            // 131072*52 (+64 pad)
  float* ctxg = g + (size_t)NROW * GST + 64;       // 512*257*50
  float* kqg = ctxg + (size_t)BB * 257 * HH;       // 512*10*260
  // total ~55 MB

  hipLaunchKernelGGL(k0_prep, dim3(26), dim3(256), 0, stream, W_in, W_ctx,
                     W_key, W_q, b_key, b_q, WHT, WK2T, bias2);
  hipLaunchKernelGGL(k1_mfma, dim3(512), dim3(256), 0, stream, x, W_in, WHT,
                     b_in, b_ctx, g);
  hipLaunchKernelGGL(k2_rec, dim3(512), dim3(64), 0, stream, g, WK2T, bias2,
                     fc, ctxg, kqg);
  hipLaunchKernelGGL(k3_attn, dim3(2048), dim3(256), 0, stream, ctxg, kqg,
                     W_act, b_act, out);
}